// Round 6
// baseline (314.006 us; speedup 1.0000x reference)
//
#include <hip/hip_runtime.h>
#include <math.h>

typedef __attribute__((ext_vector_type(8))) __bf16 bf16x8;
typedef __attribute__((ext_vector_type(4))) float f32x4;
typedef __attribute__((ext_vector_type(4))) unsigned short us4;
typedef unsigned short u16;
typedef unsigned int u32;

#define DEVI static __device__ __forceinline__

// round-to-nearest-even fp32 -> bf16
DEVI u16 f2bf(float f) {
  union { float f; unsigned u; } v; v.f = f;
  unsigned r = v.u + 0x7fffu + ((v.u >> 16) & 1u);
  return (u16)(r >> 16);
}

DEVI void async16(const void* g, void* l) {
  __builtin_amdgcn_global_load_lds((const __attribute__((address_space(1))) void*)g,
                                   (__attribute__((address_space(3))) void*)l, 16, 0, 0);
}

// pack two f32 -> one u32 of 2 bf16 (RNE)
DEVI u32 pkbf(float lo, float hi) {
  u32 r;
  asm("v_cvt_pk_bf16_f32 %0, %1, %2" : "=v"(r) : "v"(lo), "v"(hi));
  return r;
}

// ---------------- cast fp32 -> bf16 ----------------
__global__ __launch_bounds__(256) void cast_bf16(const float* __restrict__ in,
                                                 u16* __restrict__ out, int n) {
  int i = (blockIdx.x * 256 + threadIdx.x) * 4;
  if (i >= n) return;
  float4 v = *(const float4*)(in + i);
  us4 o = { f2bf(v.x), f2bf(v.y), f2bf(v.z), f2bf(v.w) };
  *(us4*)(out + i) = o;
}

// ------------- 256x256 GEMM (m201 geometry): BK=64, 8 waves 2Mx4N ----------
// per-wave 128x64 output: 64 MFMA vs 24 ds_read_b128 per K-tile.
// LDS 2 x 64KB double buffer (A 32KB + B 32KB), XOR swizzle (row&7)<<4,
// inverse-swizzled global source, linear gload_lds dest (G21).
// 4 phases/K-tile: reads 12/8/4/0, 16 MFMA each; chunk issue order
// [A-lo, B0, B1, B2, B3, A-hi] -> vmcnt(4) fences at ph0/ph1 only.
// qkv=1: N=6144, 3 slabs (Q rope+scale / K rope+swz / V transp+perm).
// qkv=0: Wo, fp32 out + bias.
__global__ __launch_bounds__(512, 2)
void gemm256(const u16* __restrict__ A,
             const u16* __restrict__ W0, const u16* __restrict__ W1, const u16* __restrict__ W2,
             const float* __restrict__ biasQ, const float* __restrict__ biasK,
             const float* __restrict__ biasV,
             const float* __restrict__ cosT, const float* __restrict__ sinT,
             void* __restrict__ out0, void* __restrict__ out1, void* __restrict__ out2,
             int ntn, int qkv)
{
  __shared__ __align__(16) char lds[2 * 65536];
  const int t = threadIdx.x, w = t >> 6, lane = t & 63;
  const int lrow = lane & 15, g = lane >> 4, lk8 = g * 8;
  // XCD-stripe decode (ntn % 8 == 0 or ntn==8)
  const int xcd = blockIdx.x & 7, bi = blockIdx.x >> 3;
  const int ntpx = ntn >> 3;
  const int nt = xcd * ntpx + (ntpx > 1 ? bi % ntpx : 0);
  const int mt = ntpx > 1 ? bi / ntpx : bi;
  const int slab = qkv ? (nt >> 3) : 3;
  const u16* Bp = (slab == 1) ? W1 : (slab == 2) ? W2 : W0;
  const int brow = mt * 256;
  const int bcol = (qkv ? (nt & 7) : nt) * 256;   // weight-row offset in slab
  const int wm = w >> 2, wn = w & 3;

  // staging: chunk j (0-3: A rows 64j..; 4-7: B rows 64(j-4)..), 8KB each,
  // thread t stages 16B at LDS byte j*8192 + t*16; global src inverse-swizzled.
  u32 soff[8];
#pragma unroll
  for (int j = 0; j < 8; ++j) {
    const int q = (j & 3) * 8192 + t * 16;       // region-relative byte
    const int row = q >> 7;
    const int cb = (q ^ ((row & 7) << 4)) & 127;
    soff[j] = (u32)(((j < 4 ? brow : bcol) + row) * 2048 + (cb >> 1));
  }
  auto stage = [&](int tile, int j, char* buf) {
    const u16* src = (j < 4) ? A : Bp;
    async16(src + soff[j] + tile * 64, buf + j * 8192 + t * 16);
  };

  // fragment read offsets (swizzled): A frags mi 0-7, B frags ni 0-3, kk 0-1
  int offA[8][2], offB[4][2];
#pragma unroll
  for (int mi = 0; mi < 8; ++mi)
#pragma unroll
    for (int kk = 0; kk < 2; ++kk) {
      const int row = wm * 128 + mi * 16 + lrow;
      offA[mi][kk] = (row * 128 + (kk * 32 + lk8) * 2) ^ ((row & 7) << 4);
    }
#pragma unroll
  for (int ni = 0; ni < 4; ++ni)
#pragma unroll
    for (int kk = 0; kk < 2; ++kk) {
      const int row = wn * 64 + ni * 16 + lrow;
      offB[ni][kk] = 32768 + ((row * 128 + (kk * 32 + lk8) * 2) ^ ((row & 7) << 4));
    }

  f32x4 acc[8][4] = {};
  bf16x8 alo[4][2], ahi[4][2], bfr[4][2];

  // prologue: stage tile 0 in fence order [0,2,4,5,6,7,1,3]
  stage(0, 0, lds); stage(0, 2, lds); stage(0, 4, lds); stage(0, 5, lds);
  stage(0, 6, lds); stage(0, 7, lds); stage(0, 1, lds); stage(0, 3, lds);

  for (int tt = 0; tt < 32; ++tt) {
    char* cur = lds + (tt & 1) * 65536;
    char* nxt = lds + ((tt + 1) & 1) * 65536;
    const bool st = tt < 31;

    // ---- phase 0: stage ch0,ch2; fence first-6; read A-lo(2kk)+B(kk0); MFMA (lo,kk0)
    if (st) { stage(tt + 1, 0, nxt); stage(tt + 1, 2, nxt); }
    if (st) asm volatile("s_waitcnt vmcnt(4)" ::: "memory");
    else    asm volatile("s_waitcnt vmcnt(2)" ::: "memory");
    __builtin_amdgcn_s_barrier();
#pragma unroll
    for (int mi = 0; mi < 4; ++mi)
#pragma unroll
      for (int kk = 0; kk < 2; ++kk) alo[mi][kk] = *(const bf16x8*)(cur + offA[mi][kk]);
#pragma unroll
    for (int ni = 0; ni < 4; ++ni) bfr[ni][0] = *(const bf16x8*)(cur + offB[ni][0]);
    asm volatile("s_waitcnt lgkmcnt(0)" ::: "memory");
    __builtin_amdgcn_sched_barrier(0);
    __builtin_amdgcn_s_setprio(1);
#pragma unroll
    for (int mi = 0; mi < 4; ++mi)
#pragma unroll
      for (int ni = 0; ni < 4; ++ni)
        acc[mi][ni] = __builtin_amdgcn_mfma_f32_16x16x32_bf16(alo[mi][0], bfr[ni][0], acc[mi][ni], 0, 0, 0);
    __builtin_amdgcn_s_setprio(0);
    __builtin_amdgcn_s_barrier();

    // ---- phase 1: stage ch4,ch5; fence rest; read B(kk1)+A-hi(kk0); MFMA (lo,kk1)
    if (st) { stage(tt + 1, 4, nxt); stage(tt + 1, 5, nxt); }
    if (st) asm volatile("s_waitcnt vmcnt(4)" ::: "memory");
    else    asm volatile("s_waitcnt vmcnt(0)" ::: "memory");
    __builtin_amdgcn_s_barrier();
#pragma unroll
    for (int ni = 0; ni < 4; ++ni) bfr[ni][1] = *(const bf16x8*)(cur + offB[ni][1]);
#pragma unroll
    for (int mi = 0; mi < 4; ++mi) ahi[mi][0] = *(const bf16x8*)(cur + offA[mi + 4][0]);
    asm volatile("s_waitcnt lgkmcnt(0)" ::: "memory");
    __builtin_amdgcn_sched_barrier(0);
    __builtin_amdgcn_s_setprio(1);
#pragma unroll
    for (int mi = 0; mi < 4; ++mi)
#pragma unroll
      for (int ni = 0; ni < 4; ++ni)
        acc[mi][ni] = __builtin_amdgcn_mfma_f32_16x16x32_bf16(alo[mi][1], bfr[ni][1], acc[mi][ni], 0, 0, 0);
    __builtin_amdgcn_s_setprio(0);
    __builtin_amdgcn_s_barrier();

    // ---- phase 2: stage ch6,ch7; read A-hi(kk1); MFMA (hi,kk0)
    if (st) { stage(tt + 1, 6, nxt); stage(tt + 1, 7, nxt); }
#pragma unroll
    for (int mi = 0; mi < 4; ++mi) ahi[mi][1] = *(const bf16x8*)(cur + offA[mi + 4][1]);
    __builtin_amdgcn_s_setprio(1);
#pragma unroll
    for (int mi = 0; mi < 4; ++mi)
#pragma unroll
      for (int ni = 0; ni < 4; ++ni)
        acc[mi + 4][ni] = __builtin_amdgcn_mfma_f32_16x16x32_bf16(ahi[mi][0], bfr[ni][0], acc[mi + 4][ni], 0, 0, 0);
    __builtin_amdgcn_s_setprio(0);
    __builtin_amdgcn_s_barrier();

    // ---- phase 3: stage ch1,ch3; MFMA (hi,kk1)
    if (st) { stage(tt + 1, 1, nxt); stage(tt + 1, 3, nxt); }
    asm volatile("s_waitcnt lgkmcnt(0)" ::: "memory");
    __builtin_amdgcn_sched_barrier(0);
    __builtin_amdgcn_s_setprio(1);
#pragma unroll
    for (int mi = 0; mi < 4; ++mi)
#pragma unroll
      for (int ni = 0; ni < 4; ++ni)
        acc[mi + 4][ni] = __builtin_amdgcn_mfma_f32_16x16x32_bf16(ahi[mi][1], bfr[ni][1], acc[mi + 4][ni], 0, 0, 0);
    __builtin_amdgcn_s_setprio(0);
    __builtin_amdgcn_s_barrier();
  }

  // ---- epilogue ----
  const int g4 = g * 4;
#pragma unroll
  for (int mi = 0; mi < 8; ++mi) {
#pragma unroll
    for (int ni = 0; ni < 4; ++ni) {
      f32x4 v = acc[mi][ni];
      const int row0 = brow + wm * 128 + mi * 16 + g4;
      const int cols = bcol + wn * 64 + ni * 16 + lrow;
      if (slab == 3) {
        float* O = (float*)out0;
        const float bv = biasQ[cols];
#pragma unroll
        for (int r = 0; r < 4; ++r)
          O[(size_t)(row0 + r) * 2048 + cols] = v[r] + bv;
      } else if (slab == 2) {   // V -> Vt [B,H,HD,S], pi-permuted + swizzled
        u16* O = (u16*)out2;
        const float bv = biasV[cols];
        const int h = cols >> 7, d = cols & 127;
        const int bb = row0 >> 11, s = row0 & 2047;
        us4 ov;
#pragma unroll
        for (int r = 0; r < 4; ++r) ov[r] = f2bf(v[r] + bv);
        const int l = s & 63;
        const int kt = l >> 4, g2 = (l >> 2) & 3;
        const int c = ((kt >> 1) << 5) + (g2 << 3) + ((kt & 1) << 2);
        u16* base = O + ((size_t)(bb * 16 + h) * 128 + d) * 2048 + (s & ~63);
        *(us4*)((char*)base + ((unsigned)(c << 1) ^ (unsigned)((d & 7) << 4))) = ov;
      } else {                  // Q (0) / K (1): bias + RoPE
        u16* O = (u16*)(slab ? out1 : out0);
        const float bv = slab ? biasK[cols] : biasQ[cols];
        const int h = cols >> 7, d = cols & 127;
        const float sgn = (d & 1) ? 1.f : -1.f;
        const float QSCL = 0.08838834764831845f * 1.44269504088896340f;
#pragma unroll
        for (int r = 0; r < 4; ++r) {
          const int row = row0 + r, bb = row >> 11, s = row & 2047;
          float q = v[r] + bv;
          float p = __shfl_xor(q, 1);   // partner dim d^1 lives in lane^1
          float o = q * cosT[s * 128 + d] + sgn * p * sinT[s * 128 + d];
          u16* base = O + ((size_t)(bb * 16 + h) * 2048 + s) * 128;
          if (slab == 0) {
            base[d] = f2bf(o * QSCL);
          } else {
            *(u16*)((char*)base + (((unsigned)(d << 1)) ^ (unsigned)((s & 7) << 4))) = f2bf(o);
          }
        }
      }
    }
  }
}

// ---------------- causal flash attention ----------------
// Q: [BH][S][128] bf16 pre-scaled by 1/sqrt(128)*log2e, K: row-swizzled,
// Vt: [BH][128][S] pi-permuted + swizzled. AO out: [4096][2048] bf16.
__global__ __launch_bounds__(256, 2)
void attn_fwd(const u16* __restrict__ Q, const u16* __restrict__ K,
              const u16* __restrict__ Vt, u16* __restrict__ AO)
{
  __shared__ __align__(16) u16 Ks[2][64 * 128];
  __shared__ __align__(16) u16 Vs[2][128 * 64];
  const int t = threadIdx.x, w = t >> 6, lane = t & 63;
  const int lrow = lane & 15, g = lane >> 4, lk8 = g * 8;
  const int id = blockIdx.x;
  const int bh = (id & 7) | (((id >> 3) & 3) << 3);   // XCD-local bh grouping
  const int pr = id >> 5;                              // pair index 0..15
  const u16* Qg = Q + (size_t)bh * 2048 * 128;
  const u16* Kg = K + (size_t)bh * 2048 * 128;
  const u16* Vg = Vt + (size_t)bh * 128 * 2048;
  const int bb = bh >> 4, h = bh & 15;

  for (int half = 0; half < 2; ++half) {
    const int qt = half ? (31 - pr) : pr;
    const int q0 = qt * 64, qw = q0 + w * 16;
    const int nkv = qt + 1;
    const int qg = qw + lrow;   // this lane's q-row

    bf16x8 qf[4];
#pragma unroll
    for (int c = 0; c < 4; ++c)
      qf[c] = *(const bf16x8*)(Qg + (size_t)(qw + lrow) * 128 + lk8 + c * 32);

    f32x4 acc_o[8] = {};
    float m = -1e30f, lsum = 0.f;

    auto stage = [&](int i, int b) {
#pragma unroll
      for (int r = 0; r < 4; ++r) {
        int e = (r * 256 + t) * 8;
        async16(Kg + (size_t)i * 8192 + e, &Ks[b][r * 2048 + w * 512]);
        async16(Vg + (size_t)(e >> 6) * 2048 + i * 64 + (e & 63), &Vs[b][r * 2048 + w * 512]);
      }
    };

    stage(0, 0);
    for (int i = 0; i < nkv; ++i) {
      const int cur = i & 1;
      const bool pfch = (i + 1) < nkv;
      if (pfch) stage(i + 1, cur ^ 1);
      if (pfch) asm volatile("s_waitcnt vmcnt(8)" ::: "memory");
      else      asm volatile("s_waitcnt vmcnt(0)" ::: "memory");
      __builtin_amdgcn_s_barrier();
      __builtin_amdgcn_sched_barrier(0);

      // QK^T swapped: C col = q (lane&15), row = k
      f32x4 sc[4];
      __builtin_amdgcn_s_setprio(1);
#pragma unroll
      for (int kt = 0; kt < 4; ++kt) {
        f32x4 s = {};
        const int krow = kt * 16 + lrow;
        const char* kbase = (const char*)(&Ks[cur][krow * 128]);
        const unsigned sw = (unsigned)((krow & 7) << 4);
#pragma unroll
        for (int c = 0; c < 4; ++c) {
          bf16x8 kf = *(const bf16x8*)(kbase + ((unsigned)((lk8 + c * 32) << 1) ^ sw));
          s = __builtin_amdgcn_mfma_f32_16x16x32_bf16(kf, qf[c], s, 0, 0, 0);
        }
        sc[kt] = s;
      }
      __builtin_amdgcn_s_setprio(0);

      float p[4][4];
      const bool lastblk = (i == qt);
      if (lastblk) {
#pragma unroll
        for (int kt = 0; kt < 4; ++kt)
#pragma unroll
          for (int r = 0; r < 4; ++r) {
            int kg = i * 64 + kt * 16 + g * 4 + r;
            p[kt][r] = (kg > qg) ? -1e30f : sc[kt][r];
          }
      } else {
#pragma unroll
        for (int kt = 0; kt < 4; ++kt)
#pragma unroll
          for (int r = 0; r < 4; ++r) p[kt][r] = sc[kt][r];
      }

      float mm = p[0][0];
#pragma unroll
      for (int kt = 0; kt < 4; ++kt)
#pragma unroll
        for (int r = 0; r < 4; ++r) mm = fmaxf(mm, p[kt][r]);
      mm = fmaxf(mm, __shfl_xor(mm, 16));
      mm = fmaxf(mm, __shfl_xor(mm, 32));

      float rs = 0.f;
      if (__any(mm > m + 8.f)) {
        const float mn = fmaxf(m, mm);
        const float corr = exp2f(m - mn);
        m = mn;
#pragma unroll
        for (int kt = 0; kt < 4; ++kt)
#pragma unroll
          for (int r = 0; r < 4; ++r) { p[kt][r] = exp2f(p[kt][r] - m); rs += p[kt][r]; }
        rs += __shfl_xor(rs, 16);
        rs += __shfl_xor(rs, 32);
        lsum = lsum * corr + rs;
#pragma unroll
        for (int nt = 0; nt < 8; ++nt)
#pragma unroll
          for (int r = 0; r < 4; ++r) acc_o[nt][r] *= corr;
      } else {
#pragma unroll
        for (int kt = 0; kt < 4; ++kt)
#pragma unroll
          for (int r = 0; r < 4; ++r) { p[kt][r] = exp2f(p[kt][r] - m); rs += p[kt][r]; }
        rs += __shfl_xor(rs, 16);
        rs += __shfl_xor(rs, 32);
        lsum += rs;
      }

      bf16x8 pb[2];
#pragma unroll
      for (int kc = 0; kc < 2; ++kc) {
        union { u32 d[4]; bf16x8 v; } u;
        u.d[0] = pkbf(p[2 * kc][0], p[2 * kc][1]);
        u.d[1] = pkbf(p[2 * kc][2], p[2 * kc][3]);
        u.d[2] = pkbf(p[2 * kc + 1][0], p[2 * kc + 1][1]);
        u.d[3] = pkbf(p[2 * kc + 1][2], p[2 * kc + 1][3]);
        pb[kc] = u.v;
      }

      __builtin_amdgcn_s_setprio(1);
#pragma unroll
      for (int nt = 0; nt < 8; ++nt) {
        const int vrow = nt * 16 + lrow;
        const char* vbase = (const char*)(&Vs[cur][vrow * 64]);
        const unsigned sw2 = (unsigned)((vrow & 7) << 4);
#pragma unroll
        for (int kc = 0; kc < 2; ++kc) {
          bf16x8 vf = *(const bf16x8*)(vbase + ((unsigned)((lk8 + kc * 32) << 1) ^ sw2));
          acc_o[nt] = __builtin_amdgcn_mfma_f32_16x16x32_bf16(vf, pb[kc], acc_o[nt], 0, 0, 0);
        }
      }
      __builtin_amdgcn_s_setprio(0);
      __builtin_amdgcn_s_barrier();
    }

    const float inv_l = 1.f / lsum;
#pragma unroll
    for (int nt = 0; nt < 8; ++nt) {
      us4 ov;
#pragma unroll
      for (int r = 0; r < 4; ++r) ov[r] = f2bf(acc_o[nt][r] * inv_l);
      *(us4*)(AO + ((size_t)(bb * 2048 + qg)) * 2048 + h * 128 + nt * 16 + g * 4) = ov;
    }
  }
}

// ---------------- launch ----------------
extern "C" void kernel_launch(void* const* d_in, const int* in_sizes, int n_in,
                              void* d_out, int out_size, void* d_ws, size_t ws_size,
                              hipStream_t stream) {
  const float* x    = (const float*)d_in[0];
  const float* cosT = (const float*)d_in[1];
  const float* sinT = (const float*)d_in[2];
  const float* Wq   = (const float*)d_in[4];
  const float* bq   = (const float*)d_in[5];
  const float* Wk   = (const float*)d_in[6];
  const float* bk   = (const float*)d_in[7];
  const float* Wv   = (const float*)d_in[8];
  const float* bv   = (const float*)d_in[9];
  const float* Wo   = (const float*)d_in[10];
  const float* bo   = (const float*)d_in[11];
  float* out = (float*)d_out;

  char* ws = (char*)d_ws;
  u16* xb  = (u16*)(ws);                    // 16 MB  [4096][2048]
  u16* Wqb = (u16*)(ws + (16u << 20));      // 8 MB
  u16* Wkb = (u16*)(ws + (24u << 20));
  u16* Wvb = (u16*)(ws + (32u << 20));
  u16* Wob = (u16*)(ws + (40u << 20));
  u16* Qb  = (u16*)(ws + (48u << 20));      // 16 MB [BH][S][HD] (pre-scaled)
  u16* Kb  = (u16*)(ws + (64u << 20));      // 16 MB [BH][S][HD] swizzled
  u16* Vtb = (u16*)(ws + (80u << 20));      // 16 MB [BH][HD][S] permuted+swizzled
  u16* AOb = (u16*)(ws + (96u << 20));      // 16 MB [4096][2048]

  cast_bf16<<<8192, 256, 0, stream>>>(x,  xb,  4096 * 2048);
  cast_bf16<<<4096, 256, 0, stream>>>(Wq, Wqb, 2048 * 2048);
  cast_bf16<<<4096, 256, 0, stream>>>(Wk, Wkb, 2048 * 2048);
  cast_bf16<<<4096, 256, 0, stream>>>(Wv, Wvb, 2048 * 2048);
  cast_bf16<<<4096, 256, 0, stream>>>(Wo, Wob, 2048 * 2048);

  // fused QKV: N = 6144, 16 m-tiles x 24 n-tiles = 384 blocks
  gemm256<<<384, 512, 0, stream>>>(xb, Wqb, Wkb, Wvb, bq, bk, bv, cosT, sinT,
                                   (void*)Qb, (void*)Kb, (void*)Vtb, 24, 1);

  attn_fwd<<<512, 256, 0, stream>>>(Qb, Kb, Vtb, AOb);

  // output proj: N = 2048, 16 x 8 = 128 blocks
  gemm256<<<128, 512, 0, stream>>>(AOb, Wob, Wob, Wob, bo, bo, bo, nullptr, nullptr,
                                   (void*)out, nullptr, nullptr, 8, 0);
}